// Round 9
// baseline (178.990 us; speedup 1.0000x reference)
//
#include <hip/hip_runtime.h>

#define BB 16
#define NN 1024
#define CC 64

typedef __attribute__((ext_vector_type(8))) short short8;
typedef __attribute__((ext_vector_type(4))) float f32x4;
typedef __attribute__((ext_vector_type(4))) int   i32x4;

typedef __attribute__((address_space(3))) void lds_void_t;
typedef const __attribute__((address_space(1))) void gbl_void_t;

__device__ __forceinline__ void load_lds16(const void* g, void* l) {
    __builtin_amdgcn_global_load_lds((gbl_void_t*)g, (lds_void_t*)l, 16, 0, 0);
}

__device__ __forceinline__ unsigned short bf16_rne(float f) {
    unsigned u = __float_as_uint(f);
    u += 0x7fffu + ((u >> 16) & 1u);
    return (unsigned short)(u >> 16);
}

// ---------------- Kernel 1: xw = x@W_rel -> bf16 swizzled (B-frag order);
//                  out = x@W_root + b_rel (fp32) ---------------- (unchanged)
extern "C" __global__ __launch_bounds__(256)
void precompute(const float* __restrict__ x, const float* __restrict__ W_rel,
                const float* __restrict__ W_root, const float* __restrict__ b_rel,
                unsigned short* __restrict__ xw_sw, float* __restrict__ out)
{
    __shared__ float wrel_s[64 * 64];
    __shared__ float wroot_s[64 * 64];
    __shared__ float x_s[16 * 68];

    const int t = threadIdx.x;
    #pragma unroll
    for (int k = 0; k < 4; ++k) {
        int i4 = t + 256 * k;
        ((float4*)wrel_s)[i4]  = ((const float4*)W_rel)[i4];
        ((float4*)wroot_s)[i4] = ((const float4*)W_root)[i4];
    }
    const int row0 = blockIdx.x * 16;
    {
        int r = t >> 4, c4 = t & 15;
        *(float4*)(x_s + r * 68 + c4 * 4) = ((const float4*)(x + (size_t)(row0 + r) * CC))[c4];
    }
    __syncthreads();

    const int c4 = t & 15;
    const int r  = t >> 4;
    float aw0 = 0.f, aw1 = 0.f, aw2 = 0.f, aw3 = 0.f;
    float ar0 = 0.f, ar1 = 0.f, ar2 = 0.f, ar3 = 0.f;
    const float* xrow = x_s + r * 68;
    #pragma unroll 8
    for (int k = 0; k < 64; ++k) {
        float xv = xrow[k];
        float4 wv = ((const float4*)(wrel_s  + k * 64))[c4];
        float4 rv = ((const float4*)(wroot_s + k * 64))[c4];
        aw0 += xv * wv.x; aw1 += xv * wv.y; aw2 += xv * wv.z; aw3 += xv * wv.w;
        ar0 += xv * rv.x; ar1 += xv * rv.y; ar2 += xv * rv.z; ar3 += xv * rv.w;
    }

    const int row_g = row0 + r;
    {
        const float4 bv = ((const float4*)b_rel)[c4];
        ((float4*)out)[(size_t)row_g * 16 + c4] =
            make_float4(ar0 + bv.x, ar1 + bv.y, ar2 + bv.z, ar3 + bv.w);
    }
    {
        const int b = row_g >> 10;
        const int k = row_g & 1023;
        const int kb = k >> 5;
        const int qk = (k >> 3) & 3;
        const int j  = k & 7;
        const int c  = 4 * c4;
        const int n0 = c >> 4;
        const int n  = c & 15;
        size_t off = ((size_t)b << 16) + (size_t)((kb * 4 + n0) << 9)
                   + (size_t)((n + (qk << 4)) << 3) + j;
        xw_sw[off]      = bf16_rne(aw0);
        xw_sw[off + 8]  = bf16_rne(aw1);
        xw_sw[off + 16] = bf16_rne(aw2);
        xw_sw[off + 24] = bf16_rne(aw3);
    }
}

// ---------------- Kernel 2: out += (adj .* w_edge[ea]) @ xw  (bf16 MFMA) ----
// grid = B * (N/64) = 256 blocks x 1024 threads (1 block/CU, LDS 120 KB).
// PRODUCER/CONSUMER WAVE SPECIALIZATION: waves 0-7 only stream memory
// (fire-and-forget global_load_lds into a 3-slot LDS ring, 5 DMA each per
// chunk, vmcnt(5) + raw s_barrier sync -> 2 chunks = 80 KB/CU permanently in
// flight); waves 8-15 only compute (WSEL/pack/MFMA from LDS). This keeps the
// vmem pipe issuing continuously, unlike R2-R8 where load->waitcnt->compute
// coupling capped the miss path at ~1.6 TB/s duty-cycled bandwidth.
// Chunk = 64 rows x 64 k: adj frags 16 KB | ea frags 16 KB | xw 8 KB = 40 KB.
#define SLOT_B  40960
#define EA_OFF  16384
#define XW_OFF  32768

extern "C" __global__ __launch_bounds__(1024, 4)
void gnn_mfma(const float* __restrict__ adj, const int* __restrict__ ea,
              const float* __restrict__ w_edge,
              const unsigned short* __restrict__ xw_sw,
              float* __restrict__ out)
{
    __shared__ __align__(16) char lds[3 * SLOT_B];

    const int t    = threadIdx.x;
    const int w    = t >> 6;              // 0..15
    const int lane = t & 63;
    const int m    = lane & 15;
    const int q    = lane >> 4;

    const int mtile = blockIdx.x & 15;
    const int b     = blockIdx.x >> 4;
    const int row0  = mtile << 6;
    const size_t growbase = ((size_t)b << 10) + row0;
    const char*  xwb = (const char*)xw_sw + ((size_t)b << 17);

    // cubic through (e, w_edge[e]) for e=0..3 — exact branchless gather
    const float w0 = w_edge[0], w1 = w_edge[1], w2 = w_edge[2], w3 = w_edge[3];
    const float d1 = w1 - w0;
    const float d2 = w2 - 2.f * w1 + w0;
    const float d3 = w3 - 3.f * w2 + 3.f * w1 - w0;
    const float c3 = d3 * (1.f / 6.f);
    const float c2 = 0.5f * d2 - 0.5f * d3;
    const float c1 = d1 - 0.5f * d2 + (1.f / 3.f) * d3;
    const float c0 = w0;

    const bool producer = (w < 8);
    // consumer decode
    const int cw = w - 8;
    const int mf = cw & 3;                // 16-row m-frag
    const int kh = cw >> 2;               // 32-k half of each chunk

    f32x4 acc0 = {0.f, 0.f, 0.f, 0.f};
    f32x4 acc1 = acc0, acc2 = acc0, acc3 = acc0;

    // ---- producer: issue chunk c into slot s (5 DMA, fire-and-forget) ----
    // producer wave p owns A/E frag-tile p (mf=p>>1, kb=p&1; halves 0,1) + xw piece p.
    #define ISSUE(c, s)                                                          \
    {                                                                            \
        char* slot = lds + (s) * SLOT_B;                                         \
        const int pmf = w >> 1, pkb = w & 1;                                     \
        const size_t rowb = ((growbase + (pmf << 4) + m) << 10) + ((c) << 6)     \
                          + (pkb << 5) + (q << 3);                               \
        char* adst = slot + (w << 11) + (lane << 4);                             \
        load_lds16(adj + rowb,                adst);                             \
        load_lds16(adj + rowb + 4,            adst + 1024);                      \
        load_lds16(ea  + rowb,                adst + EA_OFF);                    \
        load_lds16(ea  + rowb + 4,            adst + EA_OFF + 1024);             \
        load_lds16(xwb + ((c) << 13) + (w << 10) + (lane << 4),                  \
                   slot + XW_OFF + (w << 10) + (lane << 4));                     \
    }

    if (producer) {
        ISSUE(0, 0);
        ISSUE(1, 1);
        asm volatile("s_waitcnt vmcnt(5)" ::: "memory");   // chunk 0 complete
    }
    asm volatile("s_barrier" ::: "memory");

    int sc = 0;            // slot of chunk c
    int sp = 2;            // slot of chunk c+2
    #pragma unroll 1
    for (int c = 0; c < 16; ++c) {
        if (producer) {
            if (c + 2 < 16) ISSUE(c + 2, sp);
            if (c < 14) asm volatile("s_waitcnt vmcnt(5)" ::: "memory"); // c+1 done
            else        asm volatile("s_waitcnt vmcnt(0)" ::: "memory");
        } else {
            const char* slot = lds + sc * SLOT_B;
            const int tile = (mf << 1) + kh;
            const char* ab = slot + (tile << 11) + (lane << 4);
            f32x4 alo = *(const f32x4*)(ab);
            f32x4 ahi = *(const f32x4*)(ab + 1024);
            i32x4 elo = *(const i32x4*)(ab + EA_OFF);
            i32x4 ehi = *(const i32x4*)(ab + EA_OFF + 1024);

            #define WSEL(ev) __builtin_fmaf(__builtin_fmaf(__builtin_fmaf(c3, (float)(ev), c2), (float)(ev), c1), (float)(ev), c0)
            float p0 = alo[0] * WSEL(elo[0]);
            float p1 = alo[1] * WSEL(elo[1]);
            float p2 = alo[2] * WSEL(elo[2]);
            float p3 = alo[3] * WSEL(elo[3]);
            float p4 = ahi[0] * WSEL(ehi[0]);
            float p5 = ahi[1] * WSEL(ehi[1]);
            float p6 = ahi[2] * WSEL(ehi[2]);
            float p7 = ahi[3] * WSEL(ehi[3]);
            #undef WSEL

            union { int i[4]; short8 s8; } af;
            af.i[0] = __builtin_amdgcn_perm(__float_as_uint(p1), __float_as_uint(p0), 0x07060302u);
            af.i[1] = __builtin_amdgcn_perm(__float_as_uint(p3), __float_as_uint(p2), 0x07060302u);
            af.i[2] = __builtin_amdgcn_perm(__float_as_uint(p5), __float_as_uint(p4), 0x07060302u);
            af.i[3] = __builtin_amdgcn_perm(__float_as_uint(p7), __float_as_uint(p6), 0x07060302u);

            const char* xb = slot + XW_OFF + (kh << 12) + (lane << 4);
            short8 bf0 = *(const short8*)(xb);
            short8 bf1 = *(const short8*)(xb + 1024);
            short8 bf2 = *(const short8*)(xb + 2048);
            short8 bf3 = *(const short8*)(xb + 3072);

            acc0 = __builtin_amdgcn_mfma_f32_16x16x32_bf16(af.s8, bf0, acc0, 0, 0, 0);
            acc1 = __builtin_amdgcn_mfma_f32_16x16x32_bf16(af.s8, bf1, acc1, 0, 0, 0);
            acc2 = __builtin_amdgcn_mfma_f32_16x16x32_bf16(af.s8, bf2, acc2, 0, 0, 0);
            acc3 = __builtin_amdgcn_mfma_f32_16x16x32_bf16(af.s8, bf3, acc3, 0, 0, 0);
        }
        asm volatile("s_barrier" ::: "memory");
        sc = (sc == 2) ? 0 : sc + 1;
        sp = (sp == 2) ? 0 : sp + 1;
    }
    #undef ISSUE

    // ---- kh-pair combine via LDS (stride 68, conflict-free), plain RMW ----
    __syncthreads();                       // ring fully consumed -> reuse as scratch
    float* scratch = (float*)lds;          // 4 mf x 1088 floats = 17.4 KB
    if (!producer && kh == 1) {
        float* buf = scratch + mf * 1088;
        #pragma unroll
        for (int rg = 0; rg < 4; ++rg) {
            int rbase = (q * 4 + rg) * 68 + m;
            buf[rbase]      = acc0[rg];
            buf[rbase + 16] = acc1[rg];
            buf[rbase + 32] = acc2[rg];
            buf[rbase + 48] = acc3[rg];
        }
    }
    __syncthreads();
    if (!producer && kh == 0) {
        const float* buf = scratch + mf * 1088;
        float* obase = out + (growbase + (mf << 4)) * 64;
        #pragma unroll
        for (int rg = 0; rg < 4; ++rg) {
            int rpad = (q * 4 + rg) * 68 + m;
            int rout = (q * 4 + rg) * 64 + m;
            #pragma unroll
            for (int n0 = 0; n0 < 4; ++n0) {
                float v = (n0 == 0 ? acc0[rg] : n0 == 1 ? acc1[rg] : n0 == 2 ? acc2[rg] : acc3[rg]);
                v += buf[rpad + n0 * 16];
                obase[rout + n0 * 16] += v;   // block owns these rows: no atomics
            }
        }
    }
}

extern "C" void kernel_launch(void* const* d_in, const int* in_sizes, int n_in,
                              void* d_out, int out_size, void* d_ws, size_t ws_size,
                              hipStream_t stream) {
    const float* x      = (const float*)d_in[0];
    const float* adj    = (const float*)d_in[1];
    const int*   ea     = (const int*)  d_in[2];
    const float* W_rel  = (const float*)d_in[3];
    const float* b_rel  = (const float*)d_in[4];
    const float* W_root = (const float*)d_in[5];
    const float* w_edge = (const float*)d_in[6];
    float* out = (float*)d_out;

    unsigned short* xw_sw = (unsigned short*)d_ws;   // B*N*C bf16 = 2 MiB

    precompute<<<BB * NN / 16, 256, 0, stream>>>(x, W_rel, W_root, b_rel, xw_sw, out);
    gnn_mfma<<<BB * (NN / 64), 1024, 0, stream>>>(adj, ea, w_edge, xw_sw, out);
}